// Round 18
// baseline (291.425 us; speedup 1.0000x reference)
//
#include <hip/hip_runtime.h>
#include <math.h>

#define S_LEN 512
#define CH 8
#define NSEG 128
#define TBL_L0 -22.0f
#define TBL_INVH 4.0f
#define TBL_H 0.25f

typedef float v2f __attribute__((ext_vector_type(2)));

__device__ __forceinline__ float fast_rcp(float x) { return __builtin_amdgcn_rcpf(x); }
__device__ __forceinline__ float fast_rsq(float x) { return __builtin_amdgcn_rsqf(x); }
__device__ __forceinline__ float exp2s(float x)    { return __builtin_amdgcn_exp2f(x); }
__device__ __forceinline__ v2f rsqv(v2f a)  { return (v2f){fast_rsq(a.x), fast_rsq(a.y)}; }
__device__ __forceinline__ v2f minv(v2f a, v2f b) { return __builtin_elementwise_min(a, b); }
__device__ __forceinline__ v2f vfma(v2f a, v2f b, v2f c) {
    return (v2f){ __builtin_fmaf(a.x, b.x, c.x), __builtin_fmaf(a.y, b.y, c.y) };
}
__device__ __forceinline__ float f6(v2f a, v2f x, v2f b, v2f y, v2f c, v2f z) {
    // sum of 3 v2f dot-pairs as one scalar fma chain
    return __builtin_fmaf(a.x, x.x, __builtin_fmaf(a.y, x.y,
           __builtin_fmaf(b.x, y.x, __builtin_fmaf(b.y, y.y,
           __builtin_fmaf(c.x, z.x, c.y * z.y)))));
}

// quad_perm DPP add (pure VALU)
template <int CTRL>
__device__ __forceinline__ float dpp_add(float v) {
    int vi = __builtin_bit_cast(int, v);
    int t  = __builtin_amdgcn_update_dpp(vi, vi, CTRL, 0xF, 0xF, true);
    return v + __builtin_bit_cast(float, t);
}

// R17 structure (rotated basis, dx staged in LDS, PWL s(l2z) table, G-fold,
// log2-kappa, barrier-free per-wave loop). R18 exact trims:
//  - 1-stage DPP reduce (32 partials, finish sums 8 float4s)
//  - fc2 + pair-sum fused into one 6-fma scalar chain per output
__global__ __launch_bounds__(128, 4) void prnn_kernel(
    const float* __restrict__ x,
    const float* __restrict__ W1,
    const float* __restrict__ W2,
    float* __restrict__ out)
{
    const double MUd = 3130.0 / 2.6;
    const double Cd  = 0.003407;
    const double K2d = 1.4426950408889634 / Cd;          // log2(e)/C
    const double S3  = 1.7320508075688772;
    const float MU      = (float)MUd;
    const float MUS3    = (float)(MUd * S3);
    const float CP      = (float)(7825.0 / 3.0);
    const float AH      = 64.8f;
    const float TMC     = (float)(3.0 * MUd * Cd);       // 3*mu*C
    const float MQ      = (float)(-K2d / (3.0 * MUd));   // -K2/(3mu)
    const float KA0     = (float)(1.4492898 + (64.8 / (3.0 * MUd)) * K2d);
    const float I3      = (float)(1.0 / 3.0);
    const float IS3     = (float)(1.0 / S3);
    const float LOG2E   = 1.4426950408889634f;
    const float LN08    = (float)(0.8 * 0.6931471805599453);

    const int tid  = threadIdx.x;
    const int lane = tid & 63;
    const int wv   = tid >> 6;
    const int b    = blockIdx.x * 2 + wv;

    __shared__ float2 xs01[2][S_LEN];        // dx0,dx1 (8 KB)
    __shared__ float  xs2g[2][S_LEN];        // dx2 (4 KB)
    __shared__ float  part[2][CH][3][33];    // 6.2 KB (32 slots + pad)
    __shared__ float2 wtab[NSEG];            // 1 KB

    // ---- build s(l2z) = A - 3muC*W(2^l2z) PWL table (startup only) ----
    {
        float wn = 0.0f;
        if (tid <= NSEG) {
            const float sarg = TBL_L0 + (float)tid * TBL_H;
            const float z = exp2s(sarg);
            float w = fmaxf(LN08 * sarg, z * (1.0f - z));
            #pragma unroll
            for (int it = 0; it < 4; ++it) {
                const float y   = exp2s(w * LOG2E);
                const float g   = w * y;
                const float F   = g - z;
                const float Fp  = g + y;
                const float den = Fp*Fp - 0.5f*((F*y)*(2.0f + w));
                w = w - (F*Fp)*fast_rcp(den);
            }
            wn = w;
            ((float*)wtab)[tid] = wn;
        }
        __syncthreads();
        float wnext = 0.0f;
        if (tid < NSEG) wnext = ((float*)wtab)[tid + 1];
        __syncthreads();
        if (tid < NSEG) {
            const float sl = -TMC * (wnext - wn) * TBL_INVH;
            const float bi = (AH - TMC * wn) - sl * (TBL_L0 + (float)tid * TBL_H);
            wtab[tid] = (float2){sl, bi};
        }
        __syncthreads();
    }

    // Rotated per-point maps
    v2f P[3], Mr[3], T3[3], pv[3];
    #pragma unroll
    for (int f = 0; f < 3; ++f) {
        const int mA = lane, mB = lane + 64;
        v2f av = (v2f){ W1[(mA*3 + 0)*3 + f], W1[(mB*3 + 0)*3 + f] };
        v2f bv = (v2f){ W1[(mA*3 + 1)*3 + f], W1[(mB*3 + 1)*3 + f] };
        v2f cv = (v2f){ W1[(mA*3 + 2)*3 + f], W1[(mB*3 + 2)*3 + f] };
        P[f]  = MU*(av + bv);
        Mr[f] = MUS3*(av - bv);
        T3[f] = MUS3*cv;
        pv[f] = CP*(av + bv);
    }
    v2f wp[3], wm[3], w3[3];
    float gsel0, gsel1, gsel2;
    {
        float G[3][3];
        #pragma unroll
        for (int o = 0; o < 3; ++o) {
            v2f w0 = (v2f){ W2[o*384 + lane*3 + 0], W2[o*384 + (lane+64)*3 + 0] };
            v2f w1 = (v2f){ W2[o*384 + lane*3 + 1], W2[o*384 + (lane+64)*3 + 1] };
            v2f wsh= (v2f){ W2[o*384 + lane*3 + 2], W2[o*384 + (lane+64)*3 + 2] };
            wp[o] = I3 *(w0 + w1);
            wm[o] = IS3*(w0 - w1);
            w3[o] = IS3*wsh;
            v2f ws = w0 + w1;
            #pragma unroll
            for (int f = 0; f < 3; ++f) {
                v2f gv = ws * pv[f];
                float g = gv.x + gv.y;
                #pragma unroll
                for (int mm = 1; mm < 64; mm <<= 1) g += __shfl_xor(g, mm, 64);
                G[o][f] = g;
            }
        }
        const int ro = lane % 3;
        gsel0 = (ro == 0) ? G[0][0] : (ro == 1) ? G[1][0] : G[2][0];
        gsel1 = (ro == 0) ? G[0][1] : (ro == 1) ? G[1][1] : G[2][1];
        gsel2 = (ro == 0) ? G[0][2] : (ro == 1) ? G[1][2] : G[2][2];
    }

    // Per-wave dx staging (same wave writes then reads -> DS program order)
    const float* xb = x + (size_t)b * (S_LEN*3);
    for (int i = lane; i < S_LEN; i += 64) {
        const float c0 = xb[i*3 + 0], c1 = xb[i*3 + 1], c2 = xb[i*3 + 2];
        float p0 = 0.f, p1 = 0.f, p2 = 0.f;
        if (i > 0) { p0 = xb[i*3 - 3]; p1 = xb[i*3 - 2]; p2 = xb[i*3 - 1]; }
        xs01[wv][i] = (float2){ c0 - p0, c1 - p1 };
        xs2g[wv][i] = c2 - p2;
    }

    v2f sp = (v2f){0.f,0.f}, sm = sp, s3 = sp;
    v2f ka2 = (v2f){KA0, KA0};
    float* outb = out + (size_t)b * (S_LEN*3);
    const int rtt0 = (lane < 24) ? (lane / 3) : 0;

    #pragma unroll 1
    for (int tc = 0; tc < S_LEN; tc += CH) {
        // prefetch finish-block absolute x (3 scalars, hidden under the body)
        const float* xrow = xb + (size_t)(tc + rtt0)*3;
        const float fx0 = xrow[0], fx1 = xrow[1], fx2 = xrow[2];

        #pragma unroll
        for (int tt = 0; tt < CH; ++tt) {
            const int t = tc + tt;
            const float2 dx01 = xs01[wv][t];
            const float  dx2  = xs2g[wv][t];
            const float dx0 = dx01.x, dx1 = dx01.y;

            // rotated trial: (p, m, d3) = R*dx + state
            v2f p  = P[0]*dx0 + P[1]*dx1 + P[2]*dx2 + sp;
            v2f m  = Mr[0]*dx0 + Mr[1]*dx1 + Mr[2]*dx2 + sm;
            v2f d3 = T3[0]*dx0 + T3[1]*dx1 + T3[2]*dx2 + s3;

            // q^2 = p^2 + m^2 + d3^2 + eps
            v2f h = vfma(p, p, vfma(m, m, vfma(d3, d3, (v2f){1e-24f,1e-24f})));
            v2f qi = rsqv(h);
            v2f q  = h * qi;

            // s = A - 3muC*W(2^l2z); l2z = q*MQ + ka2
            v2f g   = q * MQ;
            v2f l2z = g + ka2;
            const float fix = __builtin_fmaf(l2z.x, TBL_INVH*8.0f, -TBL_L0*TBL_INVH*8.0f);
            const float fiy = __builtin_fmaf(l2z.y, TBL_INVH*8.0f, -TBL_L0*TBL_INVH*8.0f);
            const unsigned bx = (unsigned)fix & 0xFFFFFFF8u;  // byte offset, saturating cvt
            const unsigned by = (unsigned)fiy & 0xFFFFFFF8u;
            const float2 tx = *(const float2*)((const char*)wtab + bx);
            const float2 ty = *(const float2*)((const char*)wtab + by);
            v2f sv = (v2f){ __builtin_fmaf(tx.x, l2z.x, tx.y),
                            __builtin_fmaf(ty.x, l2z.y, ty.y) };
            v2f u   = minv(sv*qi, (v2f){1.0f,1.0f});
            ka2 = vfma(-u, g, l2z);              // exact: ka2 + MQ*max(q-s,0)

            // radial return in rotated basis
            sp = u*p; sm = u*m; s3 = u*d3;

            // fc2 + pair-sum fused: one 6-fma chain per output
            float c0 = f6(wp[0], sp, wm[0], sm, w3[0], s3);
            float c1 = f6(wp[1], sp, wm[1], sm, w3[1], s3);
            float c2 = f6(wp[2], sp, wm[2], sm, w3[2], s3);

            // 1-stage DPP reduce (pairs) -> 32 partials
            c0 = dpp_add<0xB1>(c0);
            c1 = dpp_add<0xB1>(c1);
            c2 = dpp_add<0xB1>(c2);
            if ((lane & 1) == 0) {
                const int g32 = lane >> 1;       // 0..31
                part[wv][tt][0][g32] = c0;
                part[wv][tt][1][g32] = c1;
                part[wv][tt][2][g32] = c2;
            }
        }
        // finish (same wave, DS program order): lane r<24 -> (tt=r/3, o=r%3)
        if (lane < 24) {
            const int rtt = lane / 3, ro = lane - rtt*3;
            const float4* pp = (const float4*)&part[wv][rtt][ro][0];
            float s = 0.0f;
            #pragma unroll
            for (int k = 0; k < 8; ++k) {
                const float4 v = pp[k];
                s += (v.x + v.y) + (v.z + v.w);
            }
            s = __builtin_fmaf(gsel0, fx0, s);
            s = __builtin_fmaf(gsel1, fx1, s);
            s = __builtin_fmaf(gsel2, fx2, s);
            outb[tc*3 + lane] = s;
        }
    }
}

extern "C" void kernel_launch(void* const* d_in, const int* in_sizes, int n_in,
                              void* d_out, int out_size, void* d_ws, size_t ws_size,
                              hipStream_t stream) {
    const float* x  = (const float*)d_in[0];
    const float* W1 = (const float*)d_in[1];
    const float* W2 = (const float*)d_in[2];
    float* out = (float*)d_out;
    prnn_kernel<<<2048, 128, 0, stream>>>(x, W1, W2, out);
}